// Round 7
// baseline (42.308 us; speedup 1.0000x reference)
//
#include <hip/hip_runtime.h>
#include <hip/hip_cooperative_groups.h>
#include <math.h>

namespace cg = cooperative_groups;

// Problem constants (fixed by the reference): B=2, N=64, CI=CO=32
#define NZ 2
#define NN 64
#define NCI 32
#define NCO 32
#define SLICES 32              // blocks per z; each covers 128 (c,d) pairs
// ws: folded partials part[z][sl][224]  (224 = QA[96] QB[96] gam[32])

__device__ __forceinline__ void ld4(const float* __restrict__ p, float* d) {
    const float4 v = *(const float4*)p;
    d[0] = v.x; d[1] = v.y; d[2] = v.z; d[3] = v.w;
}

// Math (everything linear in rel = r_b - r_a):
//   ft[j]   = sum_{c,d} f[c,d,j]
//   Gs[x,j] = sum_{c,d} g_c[x] * f[c,d,j]
//   Gd[x,j] = sum_{c,d} g_d[x] * f[c,d,j]
//   Qm[x,i] = sum_j Wm[x,i,j] * ft[j]
//   QA = scale*(Q1+Q2+Q3) (coeff of -g_a[x]);  QB = scale*(Q1-Q4-Q5) (+g_b[x])
//   gam[i]  = scale * sum_{x,j} [(W2+W4-W6)*Gs + (W3+W5+W6)*Gd]
//   out[z,a,b,i] = gam[i] + sum_x (g_b[x]*QB[x,i] - g_a[x]*QA[x,i])
// The fold is linear in (ft,Gs,Gd): each block folds its own disjoint slice,
// stores a 224-float partial, grid-syncs, then sums partials and writes out.
// Single cooperative dispatch: no inter-kernel gap, no redundant streaming,
// no contended atomics (R3's failure mode).
__global__ __launch_bounds__(1024) void k_coop(const float* __restrict__ feat,
                                               const float* __restrict__ geom,
                                               const float* __restrict__ W,
                                               const int* __restrict__ nnp,
                                               float* __restrict__ part,
                                               float* __restrict__ out) {
    const int bid  = blockIdx.x;
    const int z    = bid >> 5;      // 0..1
    const int s    = bid & 31;      // slice / output chunk 0..31
    const int tid  = threadIdx.x;
    const int lane = tid & 63;
    const int wv   = tid >> 6;      // 0..15
    const int cg   = tid & 7;       // channel group (j0 = cg*4)
    const int pr   = tid >> 3;      // pair-in-slice 0..127

    __shared__ float gsh[NN * 3];
    __shared__ float wred[16][7][32];
    __shared__ float sacc[7][32];
    __shared__ float gred[3][32];
    __shared__ float red4[4][224];
    __shared__ float stab[224];     // QA[96] QB[96] gam[32]

    if (tid < NN * 3) gsh[tid] = geom[z * NN * 3 + tid];
    __syncthreads();

    // ---- Phase 1: slice reduction, one float4 feature load per thread
    //      (features read exactly once grid-wide).
    const int p = s * 128 + pr;     // global pair 0..4095
    const int c = p >> 6, d = p & 63;
    float f[4];
    ld4(feat + ((size_t)z * 4096 + p) * NCI + cg * 4, f);

    float v[7][4];
    #pragma unroll
    for (int k = 0; k < 4; ++k) {
        v[0][k] = f[k];
        #pragma unroll
        for (int x = 0; x < 3; ++x) {
            v[1 + x][k] = gsh[c * 3 + x] * f[k];
            v[4 + x][k] = gsh[d * 3 + x] * f[k];
        }
    }
    // pr low bits live in lane bits 3..5 -> butterfly over 8,16,32
    #pragma unroll
    for (int q = 0; q < 7; ++q)
        #pragma unroll
        for (int k = 0; k < 4; ++k) {
            float t = v[q][k];
            t += __shfl_xor(t, 8);
            t += __shfl_xor(t, 16);
            t += __shfl_xor(t, 32);
            v[q][k] = t;
        }
    if (lane < 8) {
        #pragma unroll
        for (int q = 0; q < 7; ++q)
            #pragma unroll
            for (int k = 0; k < 4; ++k) wred[wv][q][lane * 4 + k] = v[q][k];
    }
    __syncthreads();
    if (tid < 224) {
        const int q = tid >> 5, j = tid & 31;
        float sum = 0.f;
        #pragma unroll
        for (int g = 0; g < 16; ++g) sum += wred[g][q][j];
        sacc[q][j] = sum;
    }
    __syncthreads();

    // n_norm: Python scalar -> 1-elem array; hedge int32 vs float32 bits.
    const int vn = *nnp;
    const float nnv = (vn > 0 && vn < (1 << 23)) ? (float)vn : __int_as_float(vn);
    const float scale = 1.0f / sqrtf(6.0f * nnv * nnv);

    // ---- W-fold over 768 threads = (x, i, jg); shfl-reduce over jg.
    float* slot = part + (size_t)bid * 224;
    if (tid < 768) {
        const int x = tid >> 8, i = (tid >> 3) & 31, jg = tid & 7;
        const float* Wp = W + x * 6 * NCO * NCI + i * NCI + jg * 4;  // m stride 1024
        float w[6][4];
        #pragma unroll
        for (int m = 0; m < 6; ++m) ld4(Wp + m * 1024, w[m]);
        float q1 = 0.f, q23 = 0.f, q45 = 0.f, gp = 0.f;
        #pragma unroll
        for (int k = 0; k < 4; ++k) {
            const int j = jg * 4 + k;
            const float ftj = sacc[0][j];
            const float gsj = sacc[1 + x][j];
            const float gdj = sacc[4 + x][j];
            q1  = fmaf(w[0][k], ftj, q1);
            q23 = fmaf(w[1][k] + w[2][k], ftj, q23);
            q45 = fmaf(w[3][k] + w[4][k], ftj, q45);
            gp  = fmaf(w[1][k] + w[3][k] - w[5][k], gsj, gp);
            gp  = fmaf(w[2][k] + w[4][k] + w[5][k], gdj, gp);
        }
        #pragma unroll
        for (int m = 1; m <= 4; m <<= 1) {
            q1  += __shfl_xor(q1, m);
            q23 += __shfl_xor(q23, m);
            q45 += __shfl_xor(q45, m);
            gp  += __shfl_xor(gp, m);
        }
        if (jg == 0) {
            slot[x * 32 + i]      = scale * (q1 + q23);   // QA partial
            slot[96 + x * 32 + i] = scale * (q1 - q45);   // QB partial
            gred[x][i] = gp;
        }
    }
    __syncthreads();
    if (tid < 32)
        slot[192 + tid] = scale * (gred[0][tid] + gred[1][tid] + gred[2][tid]);

    // ---- Grid barrier: runtime-managed, handles device-scope visibility.
    cg::this_grid().sync();

    // ---- Phase 2: table = sum of this z's 32 partials, then write output.
    if (tid < 896) {
        const int e = tid >> 2, sg = tid & 3;
        const float* pz = part + ((size_t)z * 32 + sg * 8) * 224 + e;
        float sum = 0.f;
        #pragma unroll
        for (int t = 0; t < 8; ++t) sum += pz[t * 224];
        red4[sg][e] = sum;
    }
    __syncthreads();
    if (tid < 224)
        stab[tid] = red4[0][tid] + red4[1][tid] + red4[2][tid] + red4[3][tid];
    __syncthreads();

    const int i0 = cg * 4;
    const int ab = s * 128 + pr;        // 0..4095
    const int a = ab >> 6, b = ab & 63;
    float o4[4];
    #pragma unroll
    for (int k = 0; k < 4; ++k) o4[k] = stab[192 + i0 + k];
    #pragma unroll
    for (int x = 0; x < 3; ++x) {
        const float gb = gsh[b * 3 + x], ga = gsh[a * 3 + x];
        #pragma unroll
        for (int k = 0; k < 4; ++k)
            o4[k] = fmaf(gb, stab[96 + x * 32 + i0 + k],
                         fmaf(-ga, stab[x * 32 + i0 + k], o4[k]));
    }
    float4 o; o.x = o4[0]; o.y = o4[1]; o.z = o4[2]; o.w = o4[3];
    *(float4*)(out + ((size_t)(z * 4096 + ab)) * NCI + i0) = o;
}

extern "C" void kernel_launch(void* const* d_in, const int* in_sizes, int n_in,
                              void* d_out, int out_size, void* d_ws, size_t ws_size,
                              hipStream_t stream) {
    const float* feat = (const float*)d_in[0];   // [2,64,64,32]
    const float* geom = (const float*)d_in[1];   // [2,64,3]
    const float* W    = (const float*)d_in[2];   // [3,6144]
    const int*   nnp  = (const int*)d_in[3];     // scalar n_norm

    float* part = (float*)d_ws;                  // [2][32][224] folded partials
    float* outp = (float*)d_out;

    void* args[] = { (void*)&feat, (void*)&geom, (void*)&W, (void*)&nnp,
                     (void*)&part, (void*)&outp };
    hipLaunchCooperativeKernel((const void*)k_coop, dim3(NZ * SLICES),
                               dim3(1024), args, 0, stream);
}

// Round 8
// 14.708 us; speedup vs baseline: 2.8766x; 2.8766x over previous
//
#include <hip/hip_runtime.h>
#include <math.h>

// Problem constants (fixed by the reference): B=2, N=64, CI=CO=32
#define NZ 2
#define NN 64
#define NCI 32
#define NCO 32
#define NBZ 32                 // blocks per z; each block -> 128 (a,b) rows

__device__ __forceinline__ void ld4(const float* __restrict__ p, float* d) {
    const float4 v = *(const float4*)p;
    d[0] = v.x; d[1] = v.y; d[2] = v.z; d[3] = v.w;
}

// Single kernel, no inter-block communication (grid barriers measured at
// +25-40 us on this chip in R3/R7 -> redundant streaming is cheaper).
// Math (everything linear in rel = r_b - r_a):
//   ft[j]   = sum_{c,d} f[c,d,j]
//   Gs[x,j] = sum_c g_c[x] * rowsum_c[j]
//   Gd[x,j] = sum_{c,d} g_d[x] * f[c,d,j]
//   Qm[x,i] = sum_j Wm[x,i,j] * ft[j]
//   QA = scale*(Q1+Q2+Q3) (coeff of -g_a[x]);  QB = scale*(Q1-Q4-Q5) (+g_b[x])
//   gam[i]  = scale * sum_{x,j} [(W2+W4-W6)*Gs + (W3+W5+W6)*Gd]
//   out[z,a,b,i] = gam[i] + sum_x (g_b[x]*QB[x,i] - g_a[x]*QA[x,i])
// Every block redundantly computes the 224-float table for its z (features
// L2-resident after cold fetch), then writes its 128-row output chunk.
__global__ __launch_bounds__(1024) void k_single(const float* __restrict__ feat,
                                                 const float* __restrict__ geom,
                                                 const float* __restrict__ W,
                                                 const int* __restrict__ nnp,
                                                 float* __restrict__ out) {
    const int bid  = blockIdx.x;
    const int z    = bid >> 5;       // 0..1
    const int s    = bid & 31;       // output chunk 0..31
    const int tid  = threadIdx.x;
    const int lane = tid & 63;
    const int wv   = tid >> 6;       // wave 0..15

    __shared__ float gsh[NN * 3];        // 192
    __shared__ float wred[16][7][32];    // 3584
    __shared__ float red4[4][224];       // 896
    __shared__ float sacc[7][32];        // 224: ft, Gs[0..2], Gd[0..2]
    __shared__ float gred[3][32];        // 96
    __shared__ float stab[224];          // QA[96] QB[96] gam[32]

    // ---- Hoisted independent loads: n_norm scalar + this thread's W slice.
    const int vn = *nnp;                 // scalar, broadcast
    float w[6][4];
    if (tid < 768) {
        const int x = tid >> 8, i = (tid >> 3) & 31, jg = tid & 7;
        const float* Wp = W + x * 6 * NCO * NCI + i * NCI + jg * 4;  // m stride 1024
        #pragma unroll
        for (int m = 0; m < 6; ++m) ld4(Wp + m * 1024, w[m]);
    }

    if (tid < NN * 3) gsh[tid] = geom[z * NN * 3 + tid];
    __syncthreads();

    // ---- Phase 1: full per-z reduction. Thread = (c, dh, cg):
    //      c = tid>>4 (0..63), dh = (tid>>3)&1, cg = tid&7 (j0 = cg*4).
    //      32 float4 loads per thread; every feature read once per block.
    const int cg = tid & 7;
    const int dh = (tid >> 3) & 1;
    const int c  = tid >> 4;
    const float gc0 = gsh[c * 3 + 0], gc1 = gsh[c * 3 + 1], gc2 = gsh[c * 3 + 2];

    float rs[4] = {0.f, 0.f, 0.f, 0.f};
    float Gd[3][4] = {{0.f}};
    const float* rowp = feat + ((size_t)z * 4096 + c * 64 + dh * 32) * NCI + cg * 4;
    #pragma unroll 8
    for (int t = 0; t < 32; ++t) {
        float f[4];
        ld4(rowp + t * NCI, f);
        const int d = dh * 32 + t;
        const float gd0 = gsh[d * 3 + 0], gd1 = gsh[d * 3 + 1], gd2 = gsh[d * 3 + 2];
        #pragma unroll
        for (int k = 0; k < 4; ++k) {
            rs[k] += f[k];
            Gd[0][k] = fmaf(gd0, f[k], Gd[0][k]);
            Gd[1][k] = fmaf(gd1, f[k], Gd[1][k]);
            Gd[2][k] = fmaf(gd2, f[k], Gd[2][k]);
        }
    }

    // Per-lane 7x4 contribution; reduce over lane bits 3..5 (dh + c low bits).
    float v[7][4];
    #pragma unroll
    for (int k = 0; k < 4; ++k) {
        v[0][k] = rs[k];
        v[1][k] = gc0 * rs[k]; v[2][k] = gc1 * rs[k]; v[3][k] = gc2 * rs[k];
        v[4][k] = Gd[0][k];    v[5][k] = Gd[1][k];    v[6][k] = Gd[2][k];
    }
    #pragma unroll
    for (int q = 0; q < 7; ++q)
        #pragma unroll
        for (int k = 0; k < 4; ++k) {
            float t = v[q][k];
            t += __shfl_xor(t, 8);
            t += __shfl_xor(t, 16);
            t += __shfl_xor(t, 32);
            v[q][k] = t;
        }
    if (lane < 8) {
        #pragma unroll
        for (int q = 0; q < 7; ++q)
            #pragma unroll
            for (int k = 0; k < 4; ++k) wred[wv][q][lane * 4 + k] = v[q][k];
    }
    __syncthreads();
    // Two-stage cross-wave reduce: 896 threads x 4 adds, then 224 x 4 adds.
    if (tid < 896) {
        const int e = tid >> 2, g0 = tid & 3;    // e = q*32+j
        const int q = e >> 5, j = e & 31;
        red4[g0][e] = wred[g0 * 4 + 0][q][j] + wred[g0 * 4 + 1][q][j]
                    + wred[g0 * 4 + 2][q][j] + wred[g0 * 4 + 3][q][j];
    }
    __syncthreads();
    if (tid < 224) {
        const int q = tid >> 5, j = tid & 31;
        sacc[q][j] = red4[0][tid] + red4[1][tid] + red4[2][tid] + red4[3][tid];
    }
    __syncthreads();

    // n_norm: Python scalar -> 1-elem array; hedge int32 vs float32 bits.
    const float nnv = (vn > 0 && vn < (1 << 23)) ? (float)vn : __int_as_float(vn);
    const float scale = 1.0f / sqrtf(6.0f * nnv * nnv);

    // ---- Phase 2: fold W (already in registers), 768 threads = (x, i, jg).
    if (tid < 768) {
        const int x = tid >> 8, i = (tid >> 3) & 31, jg = tid & 7;
        float q1 = 0.f, q23 = 0.f, q45 = 0.f, gp = 0.f;
        #pragma unroll
        for (int k = 0; k < 4; ++k) {
            const int j = jg * 4 + k;
            const float ftj = sacc[0][j];
            const float gsj = sacc[1 + x][j];
            const float gdj = sacc[4 + x][j];
            q1  = fmaf(w[0][k], ftj, q1);
            q23 = fmaf(w[1][k] + w[2][k], ftj, q23);
            q45 = fmaf(w[3][k] + w[4][k], ftj, q45);
            gp  = fmaf(w[1][k] + w[3][k] - w[5][k], gsj, gp);
            gp  = fmaf(w[2][k] + w[4][k] + w[5][k], gdj, gp);
        }
        // jg lives in lane bits 0..2 -> butterfly over 1,2,4
        #pragma unroll
        for (int m = 1; m <= 4; m <<= 1) {
            q1  += __shfl_xor(q1, m);
            q23 += __shfl_xor(q23, m);
            q45 += __shfl_xor(q45, m);
            gp  += __shfl_xor(gp, m);
        }
        if (jg == 0) {
            stab[x * 32 + i]      = scale * (q1 + q23);   // QA
            stab[96 + x * 32 + i] = scale * (q1 - q45);   // QB
            gred[x][i] = gp;
        }
    }
    __syncthreads();
    if (tid < 32) stab[192 + tid] = scale * (gred[0][tid] + gred[1][tid] + gred[2][tid]);
    __syncthreads();

    // ---- Phase 3: 128 rows x 8 channel-groups -> one float4 store/thread.
    const int r  = tid >> 3;            // 0..127
    const int ab = s * 128 + r;         // 0..4095
    const int a = ab >> 6, b = ab & 63;
    const int i0 = cg * 4;
    float o4[4];
    #pragma unroll
    for (int k = 0; k < 4; ++k) o4[k] = stab[192 + i0 + k];
    #pragma unroll
    for (int x = 0; x < 3; ++x) {
        const float gb = gsh[b * 3 + x], ga = gsh[a * 3 + x];
        #pragma unroll
        for (int k = 0; k < 4; ++k)
            o4[k] = fmaf(gb, stab[96 + x * 32 + i0 + k],
                         fmaf(-ga, stab[x * 32 + i0 + k], o4[k]));
    }
    float4 o; o.x = o4[0]; o.y = o4[1]; o.z = o4[2]; o.w = o4[3];
    *(float4*)(out + ((size_t)(z * 4096 + ab)) * NCI + i0) = o;
}

extern "C" void kernel_launch(void* const* d_in, const int* in_sizes, int n_in,
                              void* d_out, int out_size, void* d_ws, size_t ws_size,
                              hipStream_t stream) {
    const float* feat = (const float*)d_in[0];   // [2,64,64,32]
    const float* geom = (const float*)d_in[1];   // [2,64,3]
    const float* W    = (const float*)d_in[2];   // [3,6144]
    const int*   nnp  = (const int*)d_in[3];     // scalar n_norm

    k_single<<<NZ * NBZ, 1024, 0, stream>>>(feat, geom, W, nnp, (float*)d_out);
}

// Round 9
// 14.391 us; speedup vs baseline: 2.9399x; 1.0220x over previous
//
#include <hip/hip_runtime.h>
#include <math.h>

// Problem constants (fixed by the reference): B=2, N=64, CI=CO=32
#define NZ 2
#define NN 64
#define NCI 32
#define NCO 32
#define NBZ 32                 // blocks per z; each block -> 128 (a,b) rows

__device__ __forceinline__ void ld4(const float* __restrict__ p, float* d) {
    const float4 v = *(const float4*)p;
    d[0] = v.x; d[1] = v.y; d[2] = v.z; d[3] = v.w;
}

// Single kernel, no inter-block communication. Chosen after measuring:
//   - inter-kernel dependency gap ~2.7 us (R6: two lean kernels = 14.93)
//   - atomic grid barrier +40 us (R3), cg::grid.sync +28 us (R7)
//   => zero-sync redundant reduction is cheapest on this chip.
// Math (everything linear in rel = r_b - r_a):
//   ft[j]   = sum_{c,d} f[c,d,j]
//   Gs[x,j] = sum_c g_c[x] * rowsum_c[j]
//   Gd[x,j] = sum_{c,d} g_d[x] * f[c,d,j]
//   Qm[x,i] = sum_j Wm[x,i,j] * ft[j]
//   QA = scale*(Q1+Q2+Q3) (coeff of -g_a[x]);  QB = scale*(Q1-Q4-Q5) (+g_b[x])
//   gam[i]  = scale * sum_{x,j} [(W2+W4-W6)*Gs + (W3+W5+W6)*Gd]
//   out[z,a,b,i] = gam[i] + sum_x (g_b[x]*QB[x,i] - g_a[x]*QA[x,i])
// Every block redundantly computes the 224-float table for its z (features
// L2-resident after cold fetch), then writes its 128-row output chunk.
// 1024 threads = 16 waves/CU for latency hiding on the 512 KB/block stream.
__global__ __launch_bounds__(1024) void k_single(const float* __restrict__ feat,
                                                 const float* __restrict__ geom,
                                                 const float* __restrict__ W,
                                                 const int* __restrict__ nnp,
                                                 float* __restrict__ out) {
    const int bid  = blockIdx.x;
    const int z    = bid >> 5;       // 0..1
    const int s    = bid & 31;       // output chunk 0..31
    const int tid  = threadIdx.x;
    const int lane = tid & 63;
    const int wv   = tid >> 6;       // wave 0..15

    __shared__ float gsh[NN * 3];        // 192
    __shared__ float wred[16][7][32];    // 3584
    __shared__ float sacc[7][32];        // 224: ft, Gs[0..2], Gd[0..2]
    __shared__ float gred[3][32];        // 96
    __shared__ float stab[224];          // QA[96] QB[96] gam[32]

    if (tid < NN * 3) gsh[tid] = geom[z * NN * 3 + tid];
    __syncthreads();

    // ---- Phase 1: full per-z reduction. Thread = (c, dh, cg):
    //      c = tid>>4 (0..63), dh = (tid>>3)&1 (d half), cg = tid&7 (j0=cg*4).
    //      32 float4 loads per thread, each feature read once per block.
    const int cg = tid & 7;
    const int dh = (tid >> 3) & 1;
    const int c  = tid >> 4;
    const float gc0 = gsh[c * 3 + 0], gc1 = gsh[c * 3 + 1], gc2 = gsh[c * 3 + 2];

    float rs[4] = {0.f, 0.f, 0.f, 0.f};
    float Gd[3][4] = {{0.f}};
    const float* rowp = feat + ((size_t)z * 4096 + c * 64 + dh * 32) * NCI + cg * 4;
    #pragma unroll 8
    for (int t = 0; t < 32; ++t) {
        float f[4];
        ld4(rowp + t * NCI, f);
        const int d = dh * 32 + t;
        const float gd0 = gsh[d * 3 + 0], gd1 = gsh[d * 3 + 1], gd2 = gsh[d * 3 + 2];
        #pragma unroll
        for (int k = 0; k < 4; ++k) {
            rs[k] += f[k];
            Gd[0][k] = fmaf(gd0, f[k], Gd[0][k]);
            Gd[1][k] = fmaf(gd1, f[k], Gd[1][k]);
            Gd[2][k] = fmaf(gd2, f[k], Gd[2][k]);
        }
    }

    // Per-lane 7x4 contribution; reduce over lane bits 3..5 (dh + c low bits).
    float v[7][4];
    #pragma unroll
    for (int k = 0; k < 4; ++k) {
        v[0][k] = rs[k];
        v[1][k] = gc0 * rs[k]; v[2][k] = gc1 * rs[k]; v[3][k] = gc2 * rs[k];
        v[4][k] = Gd[0][k];    v[5][k] = Gd[1][k];    v[6][k] = Gd[2][k];
    }
    #pragma unroll
    for (int q = 0; q < 7; ++q)
        #pragma unroll
        for (int k = 0; k < 4; ++k) {
            float t = v[q][k];
            t += __shfl_xor(t, 8);
            t += __shfl_xor(t, 16);
            t += __shfl_xor(t, 32);
            v[q][k] = t;
        }
    if (lane < 8) {
        #pragma unroll
        for (int q = 0; q < 7; ++q)
            #pragma unroll
            for (int k = 0; k < 4; ++k) wred[wv][q][lane * 4 + k] = v[q][k];
    }
    __syncthreads();
    if (tid < 224) {
        const int q = tid >> 5, j = tid & 31;
        float sum = 0.f;
        #pragma unroll
        for (int g = 0; g < 16; ++g) sum += wred[g][q][j];
        sacc[q][j] = sum;
    }
    __syncthreads();

    // n_norm: Python scalar -> 1-elem array; hedge int32 vs float32 bits.
    const int vn = *nnp;
    const float nnv = (vn > 0 && vn < (1 << 23)) ? (float)vn : __int_as_float(vn);
    const float scale = 1.0f / sqrtf(6.0f * nnv * nnv);

    // ---- Phase 2: fold W, parallel over 768 threads = (x, i, jg).
    //      Each thread: 6 ld4 of W + 4-j partial, then shfl-reduce over jg.
    if (tid < 768) {
        const int x = tid >> 8, i = (tid >> 3) & 31, jg = tid & 7;
        const float* Wp = W + x * 6 * NCO * NCI + i * NCI + jg * 4;  // m stride 1024
        float w[6][4];
        #pragma unroll
        for (int m = 0; m < 6; ++m) ld4(Wp + m * 1024, w[m]);
        float q1 = 0.f, q23 = 0.f, q45 = 0.f, gp = 0.f;
        #pragma unroll
        for (int k = 0; k < 4; ++k) {
            const int j = jg * 4 + k;
            const float ftj = sacc[0][j];
            const float gsj = sacc[1 + x][j];
            const float gdj = sacc[4 + x][j];
            q1  = fmaf(w[0][k], ftj, q1);
            q23 = fmaf(w[1][k] + w[2][k], ftj, q23);
            q45 = fmaf(w[3][k] + w[4][k], ftj, q45);
            gp  = fmaf(w[1][k] + w[3][k] - w[5][k], gsj, gp);
            gp  = fmaf(w[2][k] + w[4][k] + w[5][k], gdj, gp);
        }
        // jg lives in lane bits 0..2 -> butterfly over 1,2,4
        #pragma unroll
        for (int m = 1; m <= 4; m <<= 1) {
            q1  += __shfl_xor(q1, m);
            q23 += __shfl_xor(q23, m);
            q45 += __shfl_xor(q45, m);
            gp  += __shfl_xor(gp, m);
        }
        if (jg == 0) {
            stab[x * 32 + i]      = scale * (q1 + q23);   // QA
            stab[96 + x * 32 + i] = scale * (q1 - q45);   // QB
            gred[x][i] = gp;
        }
    }
    __syncthreads();
    if (tid < 32) stab[192 + tid] = scale * (gred[0][tid] + gred[1][tid] + gred[2][tid]);
    __syncthreads();

    // ---- Phase 3: 128 rows x 8 channel-groups -> one float4 store/thread.
    const int r  = tid >> 3;            // 0..127
    const int ab = s * 128 + r;         // 0..4095
    const int a = ab >> 6, b = ab & 63;
    const int i0 = cg * 4;
    float o4[4];
    #pragma unroll
    for (int k = 0; k < 4; ++k) o4[k] = stab[192 + i0 + k];
    #pragma unroll
    for (int x = 0; x < 3; ++x) {
        const float gb = gsh[b * 3 + x], ga = gsh[a * 3 + x];
        #pragma unroll
        for (int k = 0; k < 4; ++k)
            o4[k] = fmaf(gb, stab[96 + x * 32 + i0 + k],
                         fmaf(-ga, stab[x * 32 + i0 + k], o4[k]));
    }
    float4 o; o.x = o4[0]; o.y = o4[1]; o.z = o4[2]; o.w = o4[3];
    *(float4*)(out + ((size_t)(z * 4096 + ab)) * NCI + i0) = o;
}

extern "C" void kernel_launch(void* const* d_in, const int* in_sizes, int n_in,
                              void* d_out, int out_size, void* d_ws, size_t ws_size,
                              hipStream_t stream) {
    const float* feat = (const float*)d_in[0];   // [2,64,64,32]
    const float* geom = (const float*)d_in[1];   // [2,64,3]
    const float* W    = (const float*)d_in[2];   // [3,6144]
    const int*   nnp  = (const int*)d_in[3];     // scalar n_norm

    k_single<<<NZ * NBZ, 1024, 0, stream>>>(feat, geom, W, nnp, (float*)d_out);
}